// Round 28
// baseline (178.787 us; speedup 1.0000x reference)
//
#include <hip/hip_runtime.h>

#define Nn 100000
#define Ee 1600000
#define FIN 128
#define HID 128
#define CLS 64
#define NB 196       // dst buckets of 512 nodes (dst>>9)
#define BCAP 9216    // per-bucket edge capacity (mean 8163 + 11 sigma)

typedef unsigned short ushort_t;
typedef unsigned char uchar_t;
typedef unsigned int uint_t;
typedef __attribute__((ext_vector_type(8))) short bf16x8;
typedef __attribute__((ext_vector_type(4))) float f32x4;
typedef __attribute__((ext_vector_type(2))) float f32x2;

__device__ __forceinline__ ushort_t f2bf(float f) {   // RNE fp32->bf16
    uint_t u = __float_as_uint(f);
    return (ushort_t)((u + 0x7fffu + ((u >> 16) & 1u)) >> 16);
}
__device__ __forceinline__ float bflo(uint_t u) { return __uint_as_float(u << 16); }
__device__ __forceinline__ float bfhi(uint_t u) { return __uint_as_float(u & 0xffff0000u); }

// ---------------- combined front kernel ----------------

__global__ __launch_bounds__(1024) void k_front(const int* __restrict__ src,
                                                const int* __restrict__ dst,
                                                int* __restrict__ bcur,
                                                uint2* __restrict__ bedge,
                                                const float* __restrict__ x,
                                                ushort_t* __restrict__ xb,
                                                uint_t* __restrict__ xq,
                                                const float* __restrict__ W1l,
                                                const float* __restrict__ W1r,
                                                const float* __restrict__ W2l,
                                                const float* __restrict__ W2r,
                                                ushort_t* __restrict__ w1lt,
                                                ushort_t* __restrict__ w1rt,
                                                ushort_t* __restrict__ w2lt,
                                                ushort_t* __restrict__ w2rt) {
    __shared__ int h[NB];
    __shared__ int lbase[NB];
    int b = blockIdx.x;
    int t = threadIdx.x;
    if (b < NB) {
        if (t < NB) h[t] = 0;
        __syncthreads();
        int base = b * 8192;
        int bk[8], loc[8];
        #pragma unroll
        for (int it = 0; it < 8; ++it) {
            int e = base + it * 1024 + t;
            if (e < Ee) {
                bk[it] = dst[e] >> 9;
                loc[it] = atomicAdd(&h[bk[it]], 1);
            }
        }
        __syncthreads();
        if (t < NB && h[t]) lbase[t] = atomicAdd(&bcur[t], h[t]);
        __syncthreads();
        #pragma unroll
        for (int it = 0; it < 8; ++it) {
            int e = base + it * 1024 + t;
            if (e < Ee) {
                int pos = lbase[bk[it]] + loc[it];
                if (pos < BCAP)
                    bedge[(size_t)bk[it] * BCAP + pos] = make_uint2((uint_t)src[e], (uint_t)dst[e]);
            }
        }
    } else if (b < NB + 3125) {
        int i = (b - NB) * 1024 + t;
        float4 v = reinterpret_cast<const float4*>(x)[i];
        ushort4 o;
        o.x = f2bf(v.x); o.y = f2bf(v.y); o.z = f2bf(v.z); o.w = f2bf(v.w);
        reinterpret_cast<ushort4*>(xb)[i] = o;
        int q = __builtin_amdgcn_cvt_pk_fp8_f32(v.x, v.y, 0, false);
        q = __builtin_amdgcn_cvt_pk_fp8_f32(v.z, v.w, q, true);
        xq[i] = (uint_t)q;
    } else {
        int j = b - (NB + 3125);
        const float* Wsrc; ushort_t* Wdst; int Ncols; int cb;
        if (j < 16)      { Wsrc = W1l; Wdst = w1lt; Ncols = 128; cb = j; }
        else if (j < 32) { Wsrc = W1r; Wdst = w1rt; Ncols = 128; cb = j - 16; }
        else if (j < 40) { Wsrc = W2l; Wdst = w2lt; Ncols = 64;  cb = j - 32; }
        else             { Wsrc = W2r; Wdst = w2rt; Ncols = 64;  cb = j - 40; }
        int i = cb * 1024 + t;
        if (i < 128 * Ncols) {
            int k = i / Ncols, n = i % Ncols;
            Wdst[(size_t)n * 128 + k] = f2bf(Wsrc[i]);
        }
    }
}

// fused per-bucket: bucket scan -> LDS hist -> LDS scan -> rowptr -> CSR fill
__global__ __launch_bounds__(1024) void k_fillB(const uint2* __restrict__ bedge,
                                                const int* __restrict__ bcur,
                                                int* __restrict__ rowptr,
                                                int* __restrict__ csr) {
    __shared__ int h[512];
    __shared__ int off[512];
    __shared__ int sbase;
    int b = blockIdx.x, t = threadIdx.x;
    if (t < 256) off[t] = (t < NB) ? min(bcur[t], BCAP) : 0;
    __syncthreads();
    for (int o = 1; o < 256; o <<= 1) {
        int v = (t < 256 && t >= o) ? off[t - o] : 0;
        __syncthreads();
        if (t < 256) off[t] += v;
        __syncthreads();
    }
    if (t == 0) sbase = off[b] - min(bcur[b], BCAP);
    if (b == NB - 1 && t == 0) rowptr[Nn] = off[NB - 1];
    __syncthreads();
    int base_ = sbase;
    int n = min(bcur[b], BCAP);
    int node0 = b << 9;
    const uint2* be = bedge + (size_t)b * BCAP;
    if (t < 512) h[t] = 0;
    __syncthreads();
    for (int i = t; i < n; i += 1024)
        atomicAdd(&h[(int)be[i].y - node0], 1);
    __syncthreads();
    if (t < 512) off[t] = h[t];
    __syncthreads();
    for (int o = 1; o < 512; o <<= 1) {
        int v = (t < 512 && t >= o) ? off[t - o] : 0;
        __syncthreads();
        if (t < 512) off[t] += v;
        __syncthreads();
    }
    if (t < 512) {
        int excl = off[t] - h[t];
        int node = node0 + t;
        if (node < Nn) rowptr[node] = base_ + excl;
        h[t] = excl;
    }
    __syncthreads();
    for (int i = t; i < n; i += 1024) {
        uint2 ed = be[i];
        int loc = atomicAdd(&h[(int)ed.y - node0], 1);
        csr[base_ + loc] = (int)ed.x;
    }
}

// ---------------- agg1: quad-edge fp8 gather ----------------

__global__ __launch_bounds__(256) void k_agg1(const uchar_t* __restrict__ xq,
                                              const int* __restrict__ rowptr,
                                              const int* __restrict__ csr,
                                              ushort_t* __restrict__ outb) {
    int wid = (blockIdx.x * blockDim.x + threadIdx.x) >> 6;
    int lane = threadIdx.x & 63;
    if (wid >= Nn) return;
    int s0 = __builtin_amdgcn_readfirstlane(rowptr[wid]);
    int s1 = __builtin_amdgcn_readfirstlane(rowptr[wid + 1]);
    int g = lane >> 4;
    int col = lane & 15;
    const uchar_t* base = xq + col * 8;
    float a0 = 0.f, a1 = 0.f, a2 = 0.f, a3 = 0.f;
    float a4 = 0.f, a5 = 0.f, a6 = 0.f, a7 = 0.f;
    int e = s0;
    for (; e + 16 <= s1; e += 16) {
        #pragma unroll
        for (int q = 0; q < 4; ++q) {
            int i0 = __builtin_amdgcn_readfirstlane(csr[e + q * 4 + 0]);
            int i1 = __builtin_amdgcn_readfirstlane(csr[e + q * 4 + 1]);
            int i2 = __builtin_amdgcn_readfirstlane(csr[e + q * 4 + 2]);
            int i3 = __builtin_amdgcn_readfirstlane(csr[e + q * 4 + 3]);
            int id = (g & 2) ? ((g & 1) ? i3 : i2) : ((g & 1) ? i1 : i0);
            uint2 u = *reinterpret_cast<const uint2*>(base + (size_t)id * 128);
            f32x2 f0 = __builtin_amdgcn_cvt_pk_f32_fp8((int)u.x, false);
            f32x2 f1 = __builtin_amdgcn_cvt_pk_f32_fp8((int)u.x, true);
            f32x2 f2 = __builtin_amdgcn_cvt_pk_f32_fp8((int)u.y, false);
            f32x2 f3 = __builtin_amdgcn_cvt_pk_f32_fp8((int)u.y, true);
            a0 += f0.x; a1 += f0.y; a2 += f1.x; a3 += f1.y;
            a4 += f2.x; a5 += f2.y; a6 += f3.x; a7 += f3.y;
        }
    }
    for (; e + 4 <= s1; e += 4) {
        int i0 = __builtin_amdgcn_readfirstlane(csr[e + 0]);
        int i1 = __builtin_amdgcn_readfirstlane(csr[e + 1]);
        int i2 = __builtin_amdgcn_readfirstlane(csr[e + 2]);
        int i3 = __builtin_amdgcn_readfirstlane(csr[e + 3]);
        int id = (g & 2) ? ((g & 1) ? i3 : i2) : ((g & 1) ? i1 : i0);
        uint2 u = *reinterpret_cast<const uint2*>(base + (size_t)id * 128);
        f32x2 f0 = __builtin_amdgcn_cvt_pk_f32_fp8((int)u.x, false);
        f32x2 f1 = __builtin_amdgcn_cvt_pk_f32_fp8((int)u.x, true);
        f32x2 f2 = __builtin_amdgcn_cvt_pk_f32_fp8((int)u.y, false);
        f32x2 f3 = __builtin_amdgcn_cvt_pk_f32_fp8((int)u.y, true);
        a0 += f0.x; a1 += f0.y; a2 += f1.x; a3 += f1.y;
        a4 += f2.x; a5 += f2.y; a6 += f3.x; a7 += f3.y;
    }
    int rem = s1 - e;
    if (rem > 0) {
        int i0 = __builtin_amdgcn_readfirstlane(csr[e]);
        int i1 = __builtin_amdgcn_readfirstlane(csr[min(e + 1, s1 - 1)]);
        int i2 = __builtin_amdgcn_readfirstlane(csr[min(e + 2, s1 - 1)]);
        int id = (g & 2) ? i2 : ((g & 1) ? i1 : i0);
        if (g < rem) {
            uint2 u = *reinterpret_cast<const uint2*>(base + (size_t)id * 128);
            f32x2 f0 = __builtin_amdgcn_cvt_pk_f32_fp8((int)u.x, false);
            f32x2 f1 = __builtin_amdgcn_cvt_pk_f32_fp8((int)u.x, true);
            f32x2 f2 = __builtin_amdgcn_cvt_pk_f32_fp8((int)u.y, false);
            f32x2 f3 = __builtin_amdgcn_cvt_pk_f32_fp8((int)u.y, true);
            a0 += f0.x; a1 += f0.y; a2 += f1.x; a3 += f1.y;
            a4 += f2.x; a5 += f2.y; a6 += f3.x; a7 += f3.y;
        }
    }
    a0 += __shfl_xor(a0, 16); a0 += __shfl_xor(a0, 32);
    a1 += __shfl_xor(a1, 16); a1 += __shfl_xor(a1, 32);
    a2 += __shfl_xor(a2, 16); a2 += __shfl_xor(a2, 32);
    a3 += __shfl_xor(a3, 16); a3 += __shfl_xor(a3, 32);
    a4 += __shfl_xor(a4, 16); a4 += __shfl_xor(a4, 32);
    a5 += __shfl_xor(a5, 16); a5 += __shfl_xor(a5, 32);
    a6 += __shfl_xor(a6, 16); a6 += __shfl_xor(a6, 32);
    a7 += __shfl_xor(a7, 16); a7 += __shfl_xor(a7, 32);
    if (g == 0) {
        float invd = (s1 > s0) ? 1.0f / (float)(s1 - s0) : 0.0f;
        uint4 o;
        o.x = (uint_t)f2bf(a0 * invd) | ((uint_t)f2bf(a1 * invd) << 16);
        o.y = (uint_t)f2bf(a2 * invd) | ((uint_t)f2bf(a3 * invd) << 16);
        o.z = (uint_t)f2bf(a4 * invd) | ((uint_t)f2bf(a5 * invd) << 16);
        o.w = (uint_t)f2bf(a6 * invd) | ((uint_t)f2bf(a7 * invd) << 16);
        *reinterpret_cast<uint4*>(outb + (size_t)wid * 128 + col * 8) = o;
    }
}

// ---------------- fused layer-1 + layer-2 GEMM, A-fragments prefetched ----------------
// All 8 A-loads (2 pairs x 4 ks) issued to registers at kernel entry; their
// HBM/L3 latency hides under the two W-staging phases + barriers (T14 pattern).
// Math order identical to the split path -> absmax unchanged.

__global__ __launch_bounds__(512) void k_gemm12(const ushort_t* __restrict__ Ab0,
                                                const ushort_t* __restrict__ Ab1,
                                                const ushort_t* __restrict__ Wt0,
                                                const ushort_t* __restrict__ Wt1,
                                                const float* __restrict__ b1,
                                                const ushort_t* __restrict__ Wtl,
                                                const ushort_t* __restrict__ Wtr,
                                                uchar_t* __restrict__ tb8,
                                                float* __restrict__ outu) {
    __shared__ char lwc[32768];          // 32KB
    const int tid = threadIdx.x;
    int wid = tid >> 6;                  // 0..7
    int gw = blockIdx.x * 8 + wid;
    int lane = tid & 63;
    int r = lane & 15;
    int kg = lane >> 4;
    bool active = (gw < Nn / 16);
    int row0 = gw * 16;

    // prefetch all A-fragments (issue-early; consumed after staging barriers)
    bf16x8 afr0[4], afr1[4];
    if (active) {
        #pragma unroll
        for (int ks = 0; ks < 4; ++ks) {
            int kbase = ks * 32 + kg * 8;
            afr0[ks] = *reinterpret_cast<const bf16x8*>(Ab0 + (size_t)(row0 + r) * 128 + kbase);
            afr1[ks] = *reinterpret_cast<const bf16x8*>(Ab1 + (size_t)(row0 + r) * 128 + kbase);
        }
    }

    f32x4 acc[8];
    #pragma unroll
    for (int c = 0; c < 8; ++c) acc[c] = (f32x4){0.f, 0.f, 0.f, 0.f};

    #pragma unroll
    for (int pair = 0; pair < 2; ++pair) {
        const ushort_t* Wsrc = pair ? Wt1 : Wt0;
        #pragma unroll
        for (int i = 0; i < 4; ++i) {
            int c = tid + i * 512;
            int col = c >> 4;
            int kc = c & 15;
            uint4 v = *reinterpret_cast<const uint4*>(Wsrc + col * 128 + kc * 8);
            int dst = ((col << 8) | (kc << 4)) ^ ((col & 7) << 4);
            *reinterpret_cast<uint4*>(lwc + dst) = v;
        }
        __syncthreads();
        if (active) {
            #pragma unroll
            for (int ks = 0; ks < 4; ++ks) {
                bf16x8 af = pair ? afr1[ks] : afr0[ks];
                #pragma unroll
                for (int c = 0; c < 8; ++c) {
                    int boff = (((c * 16 + r) << 8) | (ks * 64 + kg * 16)) ^ ((r & 7) << 4);
                    bf16x8 bf = *reinterpret_cast<const bf16x8*>(lwc + boff);
                    acc[c] = __builtin_amdgcn_mfma_f32_16x16x32_bf16(af, bf, acc[c], 0, 0, 0);
                }
            }
        }
        __syncthreads();
    }

    if (active) {
        #pragma unroll
        for (int c = 0; c < 8; ++c) {
            float bv = b1[c * 16 + r];
            #pragma unroll
            for (int i = 0; i < 4; ++i) {
                int rl = wid * 16 + kg * 4 + i;
                int ha = ((rl << 8) | ((c * 16 + r) << 1)) ^ ((rl & 7) << 4);
                *reinterpret_cast<ushort_t*>(lwc + ha) = f2bf(fmaxf(acc[c][i] + bv, 0.f));
            }
        }
    }
    __syncthreads();
    if (!active) return;

    f32x4 accL[4], accR[4];
    #pragma unroll
    for (int c = 0; c < 4; ++c) {
        accL[c] = (f32x4){0.f, 0.f, 0.f, 0.f};
        accR[c] = (f32x4){0.f, 0.f, 0.f, 0.f};
    }
    #pragma unroll
    for (int ks = 0; ks < 4; ++ks) {
        int kbase = ks * 32 + kg * 8;
        int rl = wid * 16 + r;
        int ra = ((rl << 8) | (kbase << 1)) ^ ((r & 7) << 4);
        bf16x8 af = *reinterpret_cast<const bf16x8*>(lwc + ra);
        #pragma unroll
        for (int c = 0; c < 4; ++c) {
            bf16x8 bl = *reinterpret_cast<const bf16x8*>(Wtl + (size_t)(c * 16 + r) * 128 + kbase);
            accL[c] = __builtin_amdgcn_mfma_f32_16x16x32_bf16(af, bl, accL[c], 0, 0, 0);
            bf16x8 br = *reinterpret_cast<const bf16x8*>(Wtr + (size_t)(c * 16 + r) * 128 + kbase);
            accR[c] = __builtin_amdgcn_mfma_f32_16x16x32_bf16(af, br, accR[c], 0, 0, 0);
        }
    }
    #pragma unroll
    for (int c = 0; c < 4; ++c) {
        #pragma unroll
        for (int i = 0; i < 4; ++i) {
            int row = row0 + kg * 4 + i;
            int q = __builtin_amdgcn_cvt_pk_fp8_f32(accL[c][i], accL[c][i], 0, false);
            tb8[(size_t)row * 64 + c * 16 + r] = (uchar_t)(q & 0xff);
            outu[(size_t)row * 64 + c * 16 + r] = accR[c][i];
        }
    }
}

// ---------------- logsm: quad-edge fp8 gather + add + log_softmax ----------------

__global__ __launch_bounds__(256) void k_logsm(float* __restrict__ out,
                                               const uchar_t* __restrict__ tb8,
                                               const int* __restrict__ rowptr,
                                               const int* __restrict__ csr,
                                               const float* __restrict__ bias) {
    int wid = (blockIdx.x * blockDim.x + threadIdx.x) >> 6;
    int lane = threadIdx.x & 63;
    if (wid >= Nn) return;
    int s0 = __builtin_amdgcn_readfirstlane(rowptr[wid]);
    int s1 = __builtin_amdgcn_readfirstlane(rowptr[wid + 1]);
    int g = lane >> 4;
    int col = lane & 15;
    const uchar_t* base = tb8 + col * 4;
    float4 uo = *reinterpret_cast<const float4*>(out + (size_t)wid * 64 + col * 4);
    float4 bv = *reinterpret_cast<const float4*>(bias + col * 4);
    float a0 = 0.f, a1 = 0.f, a2 = 0.f, a3 = 0.f;
    int e = s0;
    for (; e + 16 <= s1; e += 16) {
        #pragma unroll
        for (int q = 0; q < 4; ++q) {
            int i0 = __builtin_amdgcn_readfirstlane(csr[e + q * 4 + 0]);
            int i1 = __builtin_amdgcn_readfirstlane(csr[e + q * 4 + 1]);
            int i2 = __builtin_amdgcn_readfirstlane(csr[e + q * 4 + 2]);
            int i3 = __builtin_amdgcn_readfirstlane(csr[e + q * 4 + 3]);
            int id = (g & 2) ? ((g & 1) ? i3 : i2) : ((g & 1) ? i1 : i0);
            uint_t u = *reinterpret_cast<const uint_t*>(base + (size_t)id * 64);
            f32x2 f0 = __builtin_amdgcn_cvt_pk_f32_fp8((int)u, false);
            f32x2 f1 = __builtin_amdgcn_cvt_pk_f32_fp8((int)u, true);
            a0 += f0.x; a1 += f0.y; a2 += f1.x; a3 += f1.y;
        }
    }
    for (; e + 4 <= s1; e += 4) {
        int i0 = __builtin_amdgcn_readfirstlane(csr[e + 0]);
        int i1 = __builtin_amdgcn_readfirstlane(csr[e + 1]);
        int i2 = __builtin_amdgcn_readfirstlane(csr[e + 2]);
        int i3 = __builtin_amdgcn_readfirstlane(csr[e + 3]);
        int id = (g & 2) ? ((g & 1) ? i3 : i2) : ((g & 1) ? i1 : i0);
        uint_t u = *reinterpret_cast<const uint_t*>(base + (size_t)id * 64);
        f32x2 f0 = __builtin_amdgcn_cvt_pk_f32_fp8((int)u, false);
        f32x2 f1 = __builtin_amdgcn_cvt_pk_f32_fp8((int)u, true);
        a0 += f0.x; a1 += f0.y; a2 += f1.x; a3 += f1.y;
    }
    int rem = s1 - e;
    if (rem > 0) {
        int i0 = __builtin_amdgcn_readfirstlane(csr[e]);
        int i1 = __builtin_amdgcn_readfirstlane(csr[min(e + 1, s1 - 1)]);
        int i2 = __builtin_amdgcn_readfirstlane(csr[min(e + 2, s1 - 1)]);
        int id = (g & 2) ? i2 : ((g & 1) ? i1 : i0);
        if (g < rem) {
            uint_t u = *reinterpret_cast<const uint_t*>(base + (size_t)id * 64);
            f32x2 f0 = __builtin_amdgcn_cvt_pk_f32_fp8((int)u, false);
            f32x2 f1 = __builtin_amdgcn_cvt_pk_f32_fp8((int)u, true);
            a0 += f0.x; a1 += f0.y; a2 += f1.x; a3 += f1.y;
        }
    }
    a0 += __shfl_xor(a0, 16); a0 += __shfl_xor(a0, 32);
    a1 += __shfl_xor(a1, 16); a1 += __shfl_xor(a1, 32);
    a2 += __shfl_xor(a2, 16); a2 += __shfl_xor(a2, 32);
    a3 += __shfl_xor(a3, 16); a3 += __shfl_xor(a3, 32);
    float invd = (s1 > s0) ? 1.0f / (float)(s1 - s0) : 0.0f;
    float v0 = (uo.x + a0 * invd) + bv.x;
    float v1 = (uo.y + a1 * invd) + bv.y;
    float v2 = (uo.z + a2 * invd) + bv.z;
    float v3 = (uo.w + a3 * invd) + bv.w;
    float m = fmaxf(fmaxf(v0, v1), fmaxf(v2, v3));
    #pragma unroll
    for (int off = 8; off; off >>= 1) m = fmaxf(m, __shfl_xor(m, off));
    float s_ = __expf(v0 - m) + __expf(v1 - m) + __expf(v2 - m) + __expf(v3 - m);
    #pragma unroll
    for (int off = 8; off; off >>= 1) s_ += __shfl_xor(s_, off);
    float ls = __logf(s_);
    if (g == 0) {
        float4 o;
        o.x = v0 - m - ls; o.y = v1 - m - ls;
        o.z = v2 - m - ls; o.w = v3 - m - ls;
        *reinterpret_cast<float4*>(out + (size_t)wid * 64 + col * 4) = o;
    }
}

// ---------------- launch ----------------

extern "C" void kernel_launch(void* const* d_in, const int* in_sizes, int n_in,
                              void* d_out, int out_size, void* d_ws, size_t ws_size,
                              hipStream_t stream) {
    const float* x   = (const float*)d_in[0];
    const int*   ei  = (const int*)d_in[1];
    const float* W1l = (const float*)d_in[2];
    const float* W1r = (const float*)d_in[3];
    const float* b1  = (const float*)d_in[4];
    const float* W2l = (const float*)d_in[5];
    const float* W2r = (const float*)d_in[6];
    const float* b2  = (const float*)d_in[7];
    float* out = (float*)d_out;

    char* ws = (char*)d_ws;
    int*      rowptr = (int*)(ws + 800768);        // N+1 ints -> ends 1200772
    int*      csr    = (int*)(ws + 1201152);       // E ints -> ends 7601152
    ushort_t* xb     = (ushort_t*)(ws + 7601152);  // N*128 bf16 -> ends 33201152
    ushort_t* aggb   = (ushort_t*)(ws + 33201152); // N*128 bf16 -> ends 58801152
    ushort_t* w1lt   = (ushort_t*)(ws + 58801152); // 128*128 bf16
    ushort_t* w1rt   = (ushort_t*)(ws + 58833920);
    ushort_t* w2lt   = (ushort_t*)(ws + 58866688); // 64*128 bf16
    ushort_t* w2rt   = (ushort_t*)(ws + 58883072); // ends 58899456
    uint2*    bedge  = (uint2*)(ws + 60000000);    // NB*BCAP uint2 -> ends 74450688 (dead after fillB)
    int*      bcur   = (int*)(ws + 74450688);      // NB ints -> ends 74451472
    uint_t*   xq     = (uint_t*)(ws + 74451968);   // N*128 fp8 = 12.8MB -> ends 87251968 (dead after agg1)
    uchar_t*  tb8    = (uchar_t*)(ws + 87252992);  // N*64 fp8 -> ends 93652992
    // high-water: 93652992 bytes

    const int* src = ei;
    const int* dst = ei + Ee;

    hipMemsetAsync(bcur, 0, NB * 4, stream);

    // front: edge scatter + x cvt (bf16+fp8) + weight cvt
    k_front<<<NB + 3125 + 48, 1024, 0, stream>>>(src, dst, bcur, bedge, x, xb, xq,
                                                 W1l, W1r, W2l, W2r,
                                                 w1lt, w1rt, w2lt, w2rt);
    k_fillB<<<NB, 1024, 0, stream>>>(bedge, bcur, rowptr, csr);

    // layer 1 gather (quad-edge fp8)
    k_agg1<<<(Nn + 3) / 4, 256, 0, stream>>>((const uchar_t*)xq, rowptr, csr, aggb);

    // fused layer-1 + layer-2 GEMMs (A prefetched to registers)
    k_gemm12<<<(Nn / 16 + 7) / 8, 512, 0, stream>>>(aggb, xb, w1lt, w1rt, b1,
                                                    w2lt, w2rt, tb8, out);

    // layer-2 gather (quad-edge fp8) + add + log_softmax
    k_logsm<<<(Nn + 3) / 4, 256, 0, stream>>>(out, tb8, rowptr, csr, b2);
}

// Round 29
// 177.094 us; speedup vs baseline: 1.0096x; 1.0096x over previous
//
#include <hip/hip_runtime.h>

#define Nn 100000
#define Ee 1600000
#define FIN 128
#define HID 128
#define CLS 64
#define NB 196       // dst buckets of 512 nodes (dst>>9)
#define BCAP 9216    // per-bucket edge capacity (mean 8163 + 11 sigma)

typedef unsigned short ushort_t;
typedef unsigned char uchar_t;
typedef unsigned int uint_t;
typedef __attribute__((ext_vector_type(8))) short bf16x8;
typedef __attribute__((ext_vector_type(4))) float f32x4;
typedef __attribute__((ext_vector_type(2))) float f32x2;

__device__ __forceinline__ ushort_t f2bf(float f) {   // RNE fp32->bf16
    uint_t u = __float_as_uint(f);
    return (ushort_t)((u + 0x7fffu + ((u >> 16) & 1u)) >> 16);
}
__device__ __forceinline__ float bflo(uint_t u) { return __uint_as_float(u << 16); }
__device__ __forceinline__ float bfhi(uint_t u) { return __uint_as_float(u & 0xffff0000u); }

// ---------------- combined front kernel ----------------

__global__ __launch_bounds__(1024) void k_front(const int* __restrict__ src,
                                                const int* __restrict__ dst,
                                                int* __restrict__ bcur,
                                                uint2* __restrict__ bedge,
                                                const float* __restrict__ x,
                                                ushort_t* __restrict__ xb,
                                                uint_t* __restrict__ xq,
                                                const float* __restrict__ W1l,
                                                const float* __restrict__ W1r,
                                                const float* __restrict__ W2l,
                                                const float* __restrict__ W2r,
                                                ushort_t* __restrict__ w1lt,
                                                ushort_t* __restrict__ w1rt,
                                                ushort_t* __restrict__ w2lt,
                                                ushort_t* __restrict__ w2rt) {
    __shared__ int h[NB];
    __shared__ int lbase[NB];
    int b = blockIdx.x;
    int t = threadIdx.x;
    if (b < NB) {
        if (t < NB) h[t] = 0;
        __syncthreads();
        int base = b * 8192;
        int bk[8], loc[8];
        #pragma unroll
        for (int it = 0; it < 8; ++it) {
            int e = base + it * 1024 + t;
            if (e < Ee) {
                bk[it] = dst[e] >> 9;
                loc[it] = atomicAdd(&h[bk[it]], 1);
            }
        }
        __syncthreads();
        if (t < NB && h[t]) lbase[t] = atomicAdd(&bcur[t], h[t]);
        __syncthreads();
        #pragma unroll
        for (int it = 0; it < 8; ++it) {
            int e = base + it * 1024 + t;
            if (e < Ee) {
                int pos = lbase[bk[it]] + loc[it];
                if (pos < BCAP)   // statistically impossible overflow guard
                    bedge[(size_t)bk[it] * BCAP + pos] = make_uint2((uint_t)src[e], (uint_t)dst[e]);
            }
        }
    } else if (b < NB + 3125) {
        int i = (b - NB) * 1024 + t;
        float4 v = reinterpret_cast<const float4*>(x)[i];
        ushort4 o;
        o.x = f2bf(v.x); o.y = f2bf(v.y); o.z = f2bf(v.z); o.w = f2bf(v.w);
        reinterpret_cast<ushort4*>(xb)[i] = o;
        int q = __builtin_amdgcn_cvt_pk_fp8_f32(v.x, v.y, 0, false);
        q = __builtin_amdgcn_cvt_pk_fp8_f32(v.z, v.w, q, true);
        xq[i] = (uint_t)q;
    } else {
        int j = b - (NB + 3125);
        const float* Wsrc; ushort_t* Wdst; int Ncols; int cb;
        if (j < 16)      { Wsrc = W1l; Wdst = w1lt; Ncols = 128; cb = j; }
        else if (j < 32) { Wsrc = W1r; Wdst = w1rt; Ncols = 128; cb = j - 16; }
        else if (j < 40) { Wsrc = W2l; Wdst = w2lt; Ncols = 64;  cb = j - 32; }
        else             { Wsrc = W2r; Wdst = w2rt; Ncols = 64;  cb = j - 40; }
        int i = cb * 1024 + t;
        if (i < 128 * Ncols) {
            int k = i / Ncols, n = i % Ncols;
            Wdst[(size_t)n * 128 + k] = f2bf(Wsrc[i]);
        }
    }
}

// fused per-bucket: bucket scan -> LDS hist -> LDS scan -> rowptr -> CSR fill
__global__ __launch_bounds__(1024) void k_fillB(const uint2* __restrict__ bedge,
                                                const int* __restrict__ bcur,
                                                int* __restrict__ rowptr,
                                                int* __restrict__ csr) {
    __shared__ int h[512];
    __shared__ int off[512];
    __shared__ int sbase;
    int b = blockIdx.x, t = threadIdx.x;
    if (t < 256) off[t] = (t < NB) ? min(bcur[t], BCAP) : 0;
    __syncthreads();
    for (int o = 1; o < 256; o <<= 1) {
        int v = (t < 256 && t >= o) ? off[t - o] : 0;
        __syncthreads();
        if (t < 256) off[t] += v;
        __syncthreads();
    }
    if (t == 0) sbase = off[b] - min(bcur[b], BCAP);
    if (b == NB - 1 && t == 0) rowptr[Nn] = off[NB - 1];
    __syncthreads();
    int base_ = sbase;
    int n = min(bcur[b], BCAP);
    int node0 = b << 9;
    const uint2* be = bedge + (size_t)b * BCAP;
    if (t < 512) h[t] = 0;
    __syncthreads();
    for (int i = t; i < n; i += 1024)
        atomicAdd(&h[(int)be[i].y - node0], 1);
    __syncthreads();
    if (t < 512) off[t] = h[t];
    __syncthreads();
    for (int o = 1; o < 512; o <<= 1) {
        int v = (t < 512 && t >= o) ? off[t - o] : 0;
        __syncthreads();
        if (t < 512) off[t] += v;
        __syncthreads();
    }
    if (t < 512) {
        int excl = off[t] - h[t];
        int node = node0 + t;
        if (node < Nn) rowptr[node] = base_ + excl;
        h[t] = excl;
    }
    __syncthreads();
    for (int i = t; i < n; i += 1024) {
        uint2 ed = be[i];
        int loc = atomicAdd(&h[(int)ed.y - node0], 1);
        csr[base_ + loc] = (int)ed.x;
    }
}

// ---------------- agg1: quad-edge fp8 gather ----------------

__global__ __launch_bounds__(256) void k_agg1(const uchar_t* __restrict__ xq,
                                              const int* __restrict__ rowptr,
                                              const int* __restrict__ csr,
                                              ushort_t* __restrict__ outb) {
    int wid = (blockIdx.x * blockDim.x + threadIdx.x) >> 6;
    int lane = threadIdx.x & 63;
    if (wid >= Nn) return;
    int s0 = __builtin_amdgcn_readfirstlane(rowptr[wid]);
    int s1 = __builtin_amdgcn_readfirstlane(rowptr[wid + 1]);
    int g = lane >> 4;
    int col = lane & 15;
    const uchar_t* base = xq + col * 8;
    float a0 = 0.f, a1 = 0.f, a2 = 0.f, a3 = 0.f;
    float a4 = 0.f, a5 = 0.f, a6 = 0.f, a7 = 0.f;
    int e = s0;
    for (; e + 16 <= s1; e += 16) {
        #pragma unroll
        for (int q = 0; q < 4; ++q) {
            int i0 = __builtin_amdgcn_readfirstlane(csr[e + q * 4 + 0]);
            int i1 = __builtin_amdgcn_readfirstlane(csr[e + q * 4 + 1]);
            int i2 = __builtin_amdgcn_readfirstlane(csr[e + q * 4 + 2]);
            int i3 = __builtin_amdgcn_readfirstlane(csr[e + q * 4 + 3]);
            int id = (g & 2) ? ((g & 1) ? i3 : i2) : ((g & 1) ? i1 : i0);
            uint2 u = *reinterpret_cast<const uint2*>(base + (size_t)id * 128);
            f32x2 f0 = __builtin_amdgcn_cvt_pk_f32_fp8((int)u.x, false);
            f32x2 f1 = __builtin_amdgcn_cvt_pk_f32_fp8((int)u.x, true);
            f32x2 f2 = __builtin_amdgcn_cvt_pk_f32_fp8((int)u.y, false);
            f32x2 f3 = __builtin_amdgcn_cvt_pk_f32_fp8((int)u.y, true);
            a0 += f0.x; a1 += f0.y; a2 += f1.x; a3 += f1.y;
            a4 += f2.x; a5 += f2.y; a6 += f3.x; a7 += f3.y;
        }
    }
    for (; e + 4 <= s1; e += 4) {
        int i0 = __builtin_amdgcn_readfirstlane(csr[e + 0]);
        int i1 = __builtin_amdgcn_readfirstlane(csr[e + 1]);
        int i2 = __builtin_amdgcn_readfirstlane(csr[e + 2]);
        int i3 = __builtin_amdgcn_readfirstlane(csr[e + 3]);
        int id = (g & 2) ? ((g & 1) ? i3 : i2) : ((g & 1) ? i1 : i0);
        uint2 u = *reinterpret_cast<const uint2*>(base + (size_t)id * 128);
        f32x2 f0 = __builtin_amdgcn_cvt_pk_f32_fp8((int)u.x, false);
        f32x2 f1 = __builtin_amdgcn_cvt_pk_f32_fp8((int)u.x, true);
        f32x2 f2 = __builtin_amdgcn_cvt_pk_f32_fp8((int)u.y, false);
        f32x2 f3 = __builtin_amdgcn_cvt_pk_f32_fp8((int)u.y, true);
        a0 += f0.x; a1 += f0.y; a2 += f1.x; a3 += f1.y;
        a4 += f2.x; a5 += f2.y; a6 += f3.x; a7 += f3.y;
    }
    int rem = s1 - e;
    if (rem > 0) {
        int i0 = __builtin_amdgcn_readfirstlane(csr[e]);
        int i1 = __builtin_amdgcn_readfirstlane(csr[min(e + 1, s1 - 1)]);
        int i2 = __builtin_amdgcn_readfirstlane(csr[min(e + 2, s1 - 1)]);
        int id = (g & 2) ? i2 : ((g & 1) ? i1 : i0);
        if (g < rem) {
            uint2 u = *reinterpret_cast<const uint2*>(base + (size_t)id * 128);
            f32x2 f0 = __builtin_amdgcn_cvt_pk_f32_fp8((int)u.x, false);
            f32x2 f1 = __builtin_amdgcn_cvt_pk_f32_fp8((int)u.x, true);
            f32x2 f2 = __builtin_amdgcn_cvt_pk_f32_fp8((int)u.y, false);
            f32x2 f3 = __builtin_amdgcn_cvt_pk_f32_fp8((int)u.y, true);
            a0 += f0.x; a1 += f0.y; a2 += f1.x; a3 += f1.y;
            a4 += f2.x; a5 += f2.y; a6 += f3.x; a7 += f3.y;
        }
    }
    a0 += __shfl_xor(a0, 16); a0 += __shfl_xor(a0, 32);
    a1 += __shfl_xor(a1, 16); a1 += __shfl_xor(a1, 32);
    a2 += __shfl_xor(a2, 16); a2 += __shfl_xor(a2, 32);
    a3 += __shfl_xor(a3, 16); a3 += __shfl_xor(a3, 32);
    a4 += __shfl_xor(a4, 16); a4 += __shfl_xor(a4, 32);
    a5 += __shfl_xor(a5, 16); a5 += __shfl_xor(a5, 32);
    a6 += __shfl_xor(a6, 16); a6 += __shfl_xor(a6, 32);
    a7 += __shfl_xor(a7, 16); a7 += __shfl_xor(a7, 32);
    if (g == 0) {
        float invd = (s1 > s0) ? 1.0f / (float)(s1 - s0) : 0.0f;
        uint4 o;
        o.x = (uint_t)f2bf(a0 * invd) | ((uint_t)f2bf(a1 * invd) << 16);
        o.y = (uint_t)f2bf(a2 * invd) | ((uint_t)f2bf(a3 * invd) << 16);
        o.z = (uint_t)f2bf(a4 * invd) | ((uint_t)f2bf(a5 * invd) << 16);
        o.w = (uint_t)f2bf(a6 * invd) | ((uint_t)f2bf(a7 * invd) << 16);
        *reinterpret_cast<uint4*>(outb + (size_t)wid * 128 + col * 8) = o;
    }
}

// ---------------- fused layer-1 + layer-2 GEMM (16x16x32 bf16 MFMA) ----------------
// Phase 1: h = relu(aggb@W1l + xb@W1r + b1)  (W1 pair staged in 64KB LDS, swizzled)
// LDS handoff: after barrier, W1 region is dead; waves write their bf16 h-tiles
// (16 rows x 128 cols, 4KB/wave) into the first 32KB with the same XOR swizzle.
// Phase 2: tb8 = fp8(h@W2l); outu = f32(h@W2r)  (W2 from global, L1-resident).

__global__ __launch_bounds__(512) void k_gemm12(const ushort_t* __restrict__ Ab0,
                                                const ushort_t* __restrict__ Ab1,
                                                const ushort_t* __restrict__ Wt0,
                                                const ushort_t* __restrict__ Wt1,
                                                const float* __restrict__ b1,
                                                const ushort_t* __restrict__ Wtl,
                                                const ushort_t* __restrict__ Wtr,
                                                uchar_t* __restrict__ tb8,
                                                float* __restrict__ outu) {
    __shared__ char lwc[2 * 32768];      // 64KB: phase1 W1 staging; phase2 first 32KB = h
    const int tid = threadIdx.x;
    #pragma unroll
    for (int i = 0; i < 8; ++i) {        // stage W1l+W1r (4096 16B chunks)
        int c = tid + i * 512;
        int pair = c >> 11;
        int col = (c & 2047) >> 4;
        int kc = c & 15;
        const ushort_t* Wsrc = pair ? Wt1 : Wt0;
        uint4 v = *reinterpret_cast<const uint4*>(Wsrc + col * 128 + kc * 8);
        int dst = ((pair << 15) | (col << 8) | (kc << 4)) ^ ((col & 7) << 4);
        *reinterpret_cast<uint4*>(lwc + dst) = v;
    }
    __syncthreads();

    int wid = tid >> 6;
    int gw = blockIdx.x * 8 + wid;
    int lane = tid & 63;
    int r = lane & 15;
    int kg = lane >> 4;
    bool active = (gw < Nn / 16);
    int row0 = gw * 16;

    f32x4 acc[8];
    #pragma unroll
    for (int c = 0; c < 8; ++c) acc[c] = (f32x4){0.f, 0.f, 0.f, 0.f};
    if (active) {
        #pragma unroll
        for (int pair = 0; pair < 2; ++pair) {
            const ushort_t* A = pair ? Ab1 : Ab0;
            #pragma unroll
            for (int ks = 0; ks < 4; ++ks) {
                int kbase = ks * 32 + kg * 8;
                bf16x8 af = *reinterpret_cast<const bf16x8*>(A + (size_t)(row0 + r) * 128 + kbase);
                #pragma unroll
                for (int c = 0; c < 8; ++c) {
                    int boff = ((pair << 15) | ((c * 16 + r) << 8) | (ks * 64 + kg * 16))
                               ^ ((r & 7) << 4);
                    bf16x8 bf = *reinterpret_cast<const bf16x8*>(lwc + boff);
                    acc[c] = __builtin_amdgcn_mfma_f32_16x16x32_bf16(af, bf, acc[c], 0, 0, 0);
                }
            }
        }
    }
    __syncthreads();   // all waves done reading W1 -> region reusable

    if (active) {
        // write h tile: row_local = wid*16 + kg*4 + i, col = c*16 + r (bf16, swizzled)
        #pragma unroll
        for (int c = 0; c < 8; ++c) {
            float bv = b1[c * 16 + r];
            #pragma unroll
            for (int i = 0; i < 4; ++i) {
                int rl = wid * 16 + kg * 4 + i;
                int ha = ((rl << 8) | ((c * 16 + r) << 1)) ^ ((rl & 7) << 4);
                *reinterpret_cast<ushort_t*>(lwc + ha) = f2bf(fmaxf(acc[c][i] + bv, 0.f));
            }
        }
    }
    __syncthreads();
    if (!active) return;

    // phase 2: A-fragments from own h rows (row_local = wid*16 + r)
    f32x4 accL[4], accR[4];
    #pragma unroll
    for (int c = 0; c < 4; ++c) {
        accL[c] = (f32x4){0.f, 0.f, 0.f, 0.f};
        accR[c] = (f32x4){0.f, 0.f, 0.f, 0.f};
    }
    #pragma unroll
    for (int ks = 0; ks < 4; ++ks) {
        int kbase = ks * 32 + kg * 8;
        int rl = wid * 16 + r;
        int ra = ((rl << 8) | (kbase << 1)) ^ ((r & 7) << 4);   // rl&7 == r&7
        bf16x8 af = *reinterpret_cast<const bf16x8*>(lwc + ra);
        #pragma unroll
        for (int c = 0; c < 4; ++c) {
            bf16x8 bl = *reinterpret_cast<const bf16x8*>(Wtl + (size_t)(c * 16 + r) * 128 + kbase);
            accL[c] = __builtin_amdgcn_mfma_f32_16x16x32_bf16(af, bl, accL[c], 0, 0, 0);
            bf16x8 br = *reinterpret_cast<const bf16x8*>(Wtr + (size_t)(c * 16 + r) * 128 + kbase);
            accR[c] = __builtin_amdgcn_mfma_f32_16x16x32_bf16(af, br, accR[c], 0, 0, 0);
        }
    }
    #pragma unroll
    for (int c = 0; c < 4; ++c) {
        #pragma unroll
        for (int i = 0; i < 4; ++i) {
            int row = row0 + kg * 4 + i;
            int q = __builtin_amdgcn_cvt_pk_fp8_f32(accL[c][i], accL[c][i], 0, false);
            tb8[(size_t)row * 64 + c * 16 + r] = (uchar_t)(q & 0xff);
            outu[(size_t)row * 64 + c * 16 + r] = accR[c][i];
        }
    }
}

// ---------------- logsm: quad-edge fp8 gather + add + log_softmax ----------------

__global__ __launch_bounds__(256) void k_logsm(float* __restrict__ out,
                                               const uchar_t* __restrict__ tb8,
                                               const int* __restrict__ rowptr,
                                               const int* __restrict__ csr,
                                               const float* __restrict__ bias) {
    int wid = (blockIdx.x * blockDim.x + threadIdx.x) >> 6;
    int lane = threadIdx.x & 63;
    if (wid >= Nn) return;
    int s0 = __builtin_amdgcn_readfirstlane(rowptr[wid]);
    int s1 = __builtin_amdgcn_readfirstlane(rowptr[wid + 1]);
    int g = lane >> 4;
    int col = lane & 15;
    const uchar_t* base = tb8 + col * 4;
    float4 uo = *reinterpret_cast<const float4*>(out + (size_t)wid * 64 + col * 4);
    float4 bv = *reinterpret_cast<const float4*>(bias + col * 4);
    float a0 = 0.f, a1 = 0.f, a2 = 0.f, a3 = 0.f;
    int e = s0;
    for (; e + 16 <= s1; e += 16) {
        #pragma unroll
        for (int q = 0; q < 4; ++q) {
            int i0 = __builtin_amdgcn_readfirstlane(csr[e + q * 4 + 0]);
            int i1 = __builtin_amdgcn_readfirstlane(csr[e + q * 4 + 1]);
            int i2 = __builtin_amdgcn_readfirstlane(csr[e + q * 4 + 2]);
            int i3 = __builtin_amdgcn_readfirstlane(csr[e + q * 4 + 3]);
            int id = (g & 2) ? ((g & 1) ? i3 : i2) : ((g & 1) ? i1 : i0);
            uint_t u = *reinterpret_cast<const uint_t*>(base + (size_t)id * 64);
            f32x2 f0 = __builtin_amdgcn_cvt_pk_f32_fp8((int)u, false);
            f32x2 f1 = __builtin_amdgcn_cvt_pk_f32_fp8((int)u, true);
            a0 += f0.x; a1 += f0.y; a2 += f1.x; a3 += f1.y;
        }
    }
    for (; e + 4 <= s1; e += 4) {
        int i0 = __builtin_amdgcn_readfirstlane(csr[e + 0]);
        int i1 = __builtin_amdgcn_readfirstlane(csr[e + 1]);
        int i2 = __builtin_amdgcn_readfirstlane(csr[e + 2]);
        int i3 = __builtin_amdgcn_readfirstlane(csr[e + 3]);
        int id = (g & 2) ? ((g & 1) ? i3 : i2) : ((g & 1) ? i1 : i0);
        uint_t u = *reinterpret_cast<const uint_t*>(base + (size_t)id * 64);
        f32x2 f0 = __builtin_amdgcn_cvt_pk_f32_fp8((int)u, false);
        f32x2 f1 = __builtin_amdgcn_cvt_pk_f32_fp8((int)u, true);
        a0 += f0.x; a1 += f0.y; a2 += f1.x; a3 += f1.y;
    }
    int rem = s1 - e;
    if (rem > 0) {
        int i0 = __builtin_amdgcn_readfirstlane(csr[e]);
        int i1 = __builtin_amdgcn_readfirstlane(csr[min(e + 1, s1 - 1)]);
        int i2 = __builtin_amdgcn_readfirstlane(csr[min(e + 2, s1 - 1)]);
        int id = (g & 2) ? i2 : ((g & 1) ? i1 : i0);
        if (g < rem) {
            uint_t u = *reinterpret_cast<const uint_t*>(base + (size_t)id * 64);
            f32x2 f0 = __builtin_amdgcn_cvt_pk_f32_fp8((int)u, false);
            f32x2 f1 = __builtin_amdgcn_cvt_pk_f32_fp8((int)u, true);
            a0 += f0.x; a1 += f0.y; a2 += f1.x; a3 += f1.y;
        }
    }
    a0 += __shfl_xor(a0, 16); a0 += __shfl_xor(a0, 32);
    a1 += __shfl_xor(a1, 16); a1 += __shfl_xor(a1, 32);
    a2 += __shfl_xor(a2, 16); a2 += __shfl_xor(a2, 32);
    a3 += __shfl_xor(a3, 16); a3 += __shfl_xor(a3, 32);
    float invd = (s1 > s0) ? 1.0f / (float)(s1 - s0) : 0.0f;
    float v0 = (uo.x + a0 * invd) + bv.x;
    float v1 = (uo.y + a1 * invd) + bv.y;
    float v2 = (uo.z + a2 * invd) + bv.z;
    float v3 = (uo.w + a3 * invd) + bv.w;
    float m = fmaxf(fmaxf(v0, v1), fmaxf(v2, v3));
    #pragma unroll
    for (int off = 8; off; off >>= 1) m = fmaxf(m, __shfl_xor(m, off));
    float s_ = __expf(v0 - m) + __expf(v1 - m) + __expf(v2 - m) + __expf(v3 - m);
    #pragma unroll
    for (int off = 8; off; off >>= 1) s_ += __shfl_xor(s_, off);
    float ls = __logf(s_);
    if (g == 0) {
        float4 o;
        o.x = v0 - m - ls; o.y = v1 - m - ls;
        o.z = v2 - m - ls; o.w = v3 - m - ls;
        *reinterpret_cast<float4*>(out + (size_t)wid * 64 + col * 4) = o;
    }
}

// ---------------- launch ----------------

extern "C" void kernel_launch(void* const* d_in, const int* in_sizes, int n_in,
                              void* d_out, int out_size, void* d_ws, size_t ws_size,
                              hipStream_t stream) {
    const float* x   = (const float*)d_in[0];
    const int*   ei  = (const int*)d_in[1];
    const float* W1l = (const float*)d_in[2];
    const float* W1r = (const float*)d_in[3];
    const float* b1  = (const float*)d_in[4];
    const float* W2l = (const float*)d_in[5];
    const float* W2r = (const float*)d_in[6];
    const float* b2  = (const float*)d_in[7];
    float* out = (float*)d_out;

    char* ws = (char*)d_ws;
    int*      rowptr = (int*)(ws + 800768);        // N+1 ints -> ends 1200772
    int*      csr    = (int*)(ws + 1201152);       // E ints -> ends 7601152
    ushort_t* xb     = (ushort_t*)(ws + 7601152);  // N*128 bf16 -> ends 33201152
    ushort_t* aggb   = (ushort_t*)(ws + 33201152); // N*128 bf16 -> ends 58801152
    ushort_t* w1lt   = (ushort_t*)(ws + 58801152); // 128*128 bf16
    ushort_t* w1rt   = (ushort_t*)(ws + 58833920);
    ushort_t* w2lt   = (ushort_t*)(ws + 58866688); // 64*128 bf16
    ushort_t* w2rt   = (ushort_t*)(ws + 58883072); // ends 58899456
    uint2*    bedge  = (uint2*)(ws + 60000000);    // NB*BCAP uint2 -> ends 74450688 (dead after fillB)
    int*      bcur   = (int*)(ws + 74450688);      // NB ints -> ends 74451472
    uint_t*   xq     = (uint_t*)(ws + 74451968);   // N*128 fp8 = 12.8MB -> ends 87251968 (dead after agg1)
    uchar_t*  tb8    = (uchar_t*)(ws + 87252992);  // N*64 fp8 -> ends 93652992
    // high-water: 93652992 bytes

    const int* src = ei;
    const int* dst = ei + Ee;

    hipMemsetAsync(bcur, 0, NB * 4, stream);

    // front: edge scatter + x cvt (bf16+fp8) + weight cvt
    k_front<<<NB + 3125 + 48, 1024, 0, stream>>>(src, dst, bcur, bedge, x, xb, xq,
                                                 W1l, W1r, W2l, W2r,
                                                 w1lt, w1rt, w2lt, w2rt);
    k_fillB<<<NB, 1024, 0, stream>>>(bedge, bcur, rowptr, csr);

    // layer 1 gather (quad-edge fp8)
    k_agg1<<<(Nn + 3) / 4, 256, 0, stream>>>((const uchar_t*)xq, rowptr, csr, aggb);

    // fused layer-1 + layer-2 GEMMs (h never leaves the CU)
    k_gemm12<<<(Nn / 16 + 7) / 8, 512, 0, stream>>>(aggb, xb, w1lt, w1rt, b1,
                                                    w2lt, w2rt, tb8, out);

    // layer-2 gather (quad-edge fp8) + add + log_softmax
    k_logsm<<<(Nn + 3) / 4, 256, 0, stream>>>(out, tb8, rowptr, csr, b2);
}